// Round 21
// baseline (249.624 us; speedup 1.0000x reference)
//
#include <hip/hip_runtime.h>

#define HID    128
#define SEQ    512
#define BATCH  256
#define DIM    300
#define VOCAB  50000

typedef short bf16x8 __attribute__((ext_vector_type(8)));   // 8 bf16 = 4 VGPR
typedef float f32x4  __attribute__((ext_vector_type(4)));

#define KP     320      // padded K (10 x 32)
#define LST    328      // LDS row stride in bf16 (656 B, 16B-aligned)
#define TROWS  32       // vocab rows per tile
#define NTILES ((VOCAB + TROWS - 1) / TROWS)   // 1563

__device__ __forceinline__ unsigned bf16_rtne(float v)
{
    unsigned u = __float_as_uint(v);
    return (u + 0x7FFFu + ((u >> 16) & 1u)) >> 16;
}

__device__ __forceinline__ bf16x8 pack_bf8(const float* src)
{
    union { uint4 u; bf16x8 v; } c;
    const float4 a = *(const float4*)(src);
    const float4 b = *(const float4*)(src + 4);
    c.u.x = bf16_rtne(a.x) | (bf16_rtne(a.y) << 16);
    c.u.y = bf16_rtne(a.z) | (bf16_rtne(a.w) << 16);
    c.u.z = bf16_rtne(b.x) | (bf16_rtne(b.y) << 16);
    c.u.w = bf16_rtne(b.z) | (bf16_rtne(b.w) << 16);
    return c.v;
}

// ---------------------------------------------------------------------------
// Kernel A (R15-proven, ~33 µs): persistent MFMA proj — byte-identical.
// ---------------------------------------------------------------------------
__global__ __launch_bounds__(512)
void proj_persist(const float* __restrict__ emb,
                  const float* __restrict__ Wih,
                  const float* __restrict__ bih,
                  const float* __restrict__ bhh,
                  float* __restrict__ P)
{
    __shared__ unsigned short Bt[128 * LST];       // W_ih bf16 (84 KB)
    __shared__ unsigned short At[2 * TROWS * LST]; // emb dbuf (2 x 21 KB)

    const int t   = threadIdx.x;
    const int bid = blockIdx.x;

    for (int c = t; c < 128 * 40; c += 512) {
        const int row = c / 40;
        const int ch  = c - row * 40;
        const float* src = Wih + (size_t)row * DIM;
        const int k0 = ch * 8;
        unsigned p0, p1, p2, p3;
        if (k0 + 8 <= DIM) {
            const float4 a = *(const float4*)(src + k0);
            const float4 b = *(const float4*)(src + k0 + 4);
            p0 = bf16_rtne(a.x) | (bf16_rtne(a.y) << 16);
            p1 = bf16_rtne(a.z) | (bf16_rtne(a.w) << 16);
            p2 = bf16_rtne(b.x) | (bf16_rtne(b.y) << 16);
            p3 = bf16_rtne(b.z) | (bf16_rtne(b.w) << 16);
        } else {
            unsigned q[8];
            #pragma unroll
            for (int e = 0; e < 8; ++e) {
                const int k = k0 + e;
                q[e] = (k < DIM) ? bf16_rtne(src[k]) : 0u;
            }
            p0 = q[0] | (q[1] << 16);  p1 = q[2] | (q[3] << 16);
            p2 = q[4] | (q[5] << 16);  p3 = q[6] | (q[7] << 16);
        }
        uint4 o = {p0, p1, p2, p3};
        *(uint4*)(&Bt[row * LST + k0]) = o;
    }

#define STAGE_EMB(tl, bf) do {                                                \
        const int v0_ = (tl) * TROWS;                                         \
        for (int c = t; c < TROWS * 40; c += 512) {                           \
            const int row = c / 40;                                           \
            const int ch  = c - row * 40;                                     \
            int grow = v0_ + row; if (grow > VOCAB - 1) grow = VOCAB - 1;     \
            const float* src = emb + (size_t)grow * DIM;                      \
            const int k0 = ch * 8;                                            \
            unsigned p0, p1, p2, p3;                                          \
            if (k0 + 8 <= DIM) {                                              \
                const float4 a = *(const float4*)(src + k0);                  \
                const float4 b = *(const float4*)(src + k0 + 4);              \
                p0 = bf16_rtne(a.x) | (bf16_rtne(a.y) << 16);                 \
                p1 = bf16_rtne(a.z) | (bf16_rtne(a.w) << 16);                 \
                p2 = bf16_rtne(b.x) | (bf16_rtne(b.y) << 16);                 \
                p3 = bf16_rtne(b.z) | (bf16_rtne(b.w) << 16);                 \
            } else {                                                          \
                unsigned q[8];                                                \
                _Pragma("unroll")                                             \
                for (int e = 0; e < 8; ++e) {                                 \
                    const int k = k0 + e;                                     \
                    q[e] = (k < DIM) ? bf16_rtne(src[k]) : 0u;                \
                }                                                             \
                p0 = q[0] | (q[1] << 16);  p1 = q[2] | (q[3] << 16);          \
                p2 = q[4] | (q[5] << 16);  p3 = q[6] | (q[7] << 16);          \
            }                                                                 \
            uint4 o = {p0, p1, p2, p3};                                       \
            *(uint4*)(&At[(bf) * (TROWS * LST) + row * LST + k0]) = o;        \
        }                                                                     \
    } while (0)

    const int lane = t & 63;
    const int w    = t >> 6;
    const int mt   = w >> 2;
    const int np   = w & 3;
    const int lm   = lane & 15;
    const int kg   = lane >> 4;

    STAGE_EMB(bid, 0);
    __syncthreads();

    int buf = 0;
    for (int tile = bid; tile < NTILES; tile += 256) {
        if (tile + 256 < NTILES) STAGE_EMB(tile + 256, buf ^ 1);

        const unsigned short* arow = &At[buf * (TROWS * LST)
                                         + (mt * 16 + lm) * LST + kg * 8];
        const unsigned short* brow = &Bt[(np * 32 + lm) * LST + kg * 8];

        f32x4 acc0 = {0.f,0.f,0.f,0.f}, acc1 = {0.f,0.f,0.f,0.f};
        #pragma unroll
        for (int k0 = 0; k0 < KP; k0 += 32) {
            const bf16x8 af = *(const bf16x8*)(arow + k0);
            const bf16x8 b0 = *(const bf16x8*)(brow + k0);
            const bf16x8 b1 = *(const bf16x8*)(brow + 16 * LST + k0);
            acc0 = __builtin_amdgcn_mfma_f32_16x16x32_bf16(af, b0, acc0, 0, 0, 0);
            acc1 = __builtin_amdgcn_mfma_f32_16x16x32_bf16(af, b1, acc1, 0, 0, 0);
        }

        const int rbase = tile * TROWS + mt * 16 + kg * 4;
        #pragma unroll
        for (int nt2 = 0; nt2 < 2; ++nt2) {
            const int h = (np * 2 + nt2) * 16 + lm;
            const float bb = bih[h] + bhh[h];
            const f32x4 a = nt2 ? acc1 : acc0;
            #pragma unroll
            for (int r = 0; r < 4; ++r) {
                const int row = rbase + r;
                if (row < VOCAB) P[(size_t)row * HID + h] = a[r] + bb;
            }
        }

        __syncthreads();
        buf ^= 1;
    }
#undef STAGE_EMB
}

// ---------------------------------------------------------------------------
// Kernel B: BATCHED-MFMA RNN. grid=16, 256 thr (4 waves). Block owns 16
// batch elements. Per step: Z^T = Whh · H^T via mfma_16x16x32_bf16
// (A=Whh frags in regs, B=H from LDS). Wave w: n in [32w,32w+32) (2 tiles).
// H: LDS bf16 [16 m][128 k], rows 256B (bank-neutral) + XOR swizzle
// ((m&7)<<4) on in-row byte offset -> reads/writes <=2-way (free).
// D mapping (proj-verified): col=lane&15 (m), row=(lane>>4)*4+r (n-in-tile).
// xt: direct global float4, 3-step rotating prefetch issued at step TOP
// (full step elapses before the barrier -> vmcnt drain ~0).
// ---------------------------------------------------------------------------
__device__ __forceinline__ float tanh_fast(float z)
{
    const float e = __builtin_amdgcn_exp2f(z * 2.8853900817779268f);
    return fmaf(-2.f, __builtin_amdgcn_rcpf(e + 1.f), 1.f);
}

__global__ __launch_bounds__(256)
void rnn_mfma(const int* __restrict__ x,
              const float* __restrict__ Whh,
              const float* __restrict__ P,
              const float* __restrict__ fcw,
              const float* __restrict__ fcb,
              float* __restrict__ out)
{
    __shared__ unsigned short Hb[2][16 * 128];   // 2 x 4 KB bf16, swizzled
    __shared__ int   toff2[SEQ * 16];            // [s][m], token*HID
    __shared__ float red[256];

    const int t  = threadIdx.x;                  // 0..255
    const int b0 = blockIdx.x * 16;
    const int w  = t >> 6;                       // wave 0..3
    const int m  = t & 15;                       // D col = batch elem
    const int g  = (t >> 4) & 3;                 // k-group / D row-group

    for (int c = t; c < SEQ * 16; c += 256)
        toff2[c] = x[(size_t)(b0 + (c & 15)) * SEQ + (c >> 4)] * HID;
    ((uint4*)Hb[0])[t] = uint4{0, 0, 0, 0};      // 256 x 16B = full 4 KB

    // A-fragments: Whh[n][k], n = 32w + 16*tau + m, k = kk*32 + g*8 + e
    const int nA = 32 * w + m;        // tile 0 row
    const int nB = nA + 16;           // tile 1 row
    const bf16x8 wa00 = pack_bf8(Whh + (size_t)nA * HID +  0 + g * 8);
    const bf16x8 wa01 = pack_bf8(Whh + (size_t)nA * HID + 32 + g * 8);
    const bf16x8 wa02 = pack_bf8(Whh + (size_t)nA * HID + 64 + g * 8);
    const bf16x8 wa03 = pack_bf8(Whh + (size_t)nA * HID + 96 + g * 8);
    const bf16x8 wa10 = pack_bf8(Whh + (size_t)nB * HID +  0 + g * 8);
    const bf16x8 wa11 = pack_bf8(Whh + (size_t)nB * HID + 32 + g * 8);
    const bf16x8 wa12 = pack_bf8(Whh + (size_t)nB * HID + 64 + g * 8);
    const bf16x8 wa13 = pack_bf8(Whh + (size_t)nB * HID + 96 + g * 8);
    __syncthreads();

    // LDS byte offsets (row m*256, XOR-swizzled in-row)
    const int swz  = (m & 7) << 4;
    const int rb   = m * 256;
    const int rdo0 = rb + ((  0 + g * 16) ^ swz);
    const int rdo1 = rb + (( 64 + g * 16) ^ swz);
    const int rdo2 = rb + ((128 + g * 16) ^ swz);
    const int rdo3 = rb + ((192 + g * 16) ^ swz);
    const int n00  = 32 * w + g * 4;             // tile0 n-base (this lane)
    const int n01  = n00 + 16;                   // tile1 n-base
    const int wro0 = rb + ((n00 * 2) ^ swz);
    const int wro1 = rb + ((n01 * 2) ^ swz);

    float hmax00 = -3.0e38f, hmax01 = -3.0e38f, hmax02 = -3.0e38f, hmax03 = -3.0e38f;
    float hmax10 = -3.0e38f, hmax11 = -3.0e38f, hmax12 = -3.0e38f, hmax13 = -3.0e38f;
    float hsum00 = 0.f, hsum01 = 0.f, hsum02 = 0.f, hsum03 = 0.f;
    float hsum10 = 0.f, hsum11 = 0.f, hsum12 = 0.f, hsum13 = 0.f;

    float4 xA0, xA1, xB0, xB1, xC0, xC1, xD0, xD1;
    { const int to = toff2[0 * 16 + m]; xA0 = *(const float4*)(P + to + n00); xA1 = *(const float4*)(P + to + n01); }
    { const int to = toff2[1 * 16 + m]; xB0 = *(const float4*)(P + to + n00); xB1 = *(const float4*)(P + to + n01); }
    { const int to = toff2[2 * 16 + m]; xC0 = *(const float4*)(P + to + n00); xC1 = *(const float4*)(P + to + n01); }

#define RSTEP(RD, XM0, XM1, XO0, XO1, SLD) do {                               \
        { const int to_ = toff2[(SLD) * 16 + m];                              \
          XO0 = *(const float4*)(P + to_ + n00);                              \
          XO1 = *(const float4*)(P + to_ + n01); }                            \
        const char* hrd_ = (const char*)Hb[RD];                               \
        char*       hwr_ = (char*)Hb[(RD) ^ 1];                               \
        const bf16x8 q0_ = *(const bf16x8*)(hrd_ + rdo0);                     \
        const bf16x8 q1_ = *(const bf16x8*)(hrd_ + rdo1);                     \
        const bf16x8 q2_ = *(const bf16x8*)(hrd_ + rdo2);                     \
        const bf16x8 q3_ = *(const bf16x8*)(hrd_ + rdo3);                     \
        f32x4 a0_ = {0.f, 0.f, 0.f, 0.f};                                     \
        f32x4 a1_ = {0.f, 0.f, 0.f, 0.f};                                     \
        a0_ = __builtin_amdgcn_mfma_f32_16x16x32_bf16(wa00, q0_, a0_, 0,0,0); \
        a1_ = __builtin_amdgcn_mfma_f32_16x16x32_bf16(wa10, q0_, a1_, 0,0,0); \
        a0_ = __builtin_amdgcn_mfma_f32_16x16x32_bf16(wa01, q1_, a0_, 0,0,0); \
        a1_ = __builtin_amdgcn_mfma_f32_16x16x32_bf16(wa11, q1_, a1_, 0,0,0); \
        a0_ = __builtin_amdgcn_mfma_f32_16x16x32_bf16(wa02, q2_, a0_, 0,0,0); \
        a1_ = __builtin_amdgcn_mfma_f32_16x16x32_bf16(wa12, q2_, a1_, 0,0,0); \
        a0_ = __builtin_amdgcn_mfma_f32_16x16x32_bf16(wa03, q3_, a0_, 0,0,0); \
        a1_ = __builtin_amdgcn_mfma_f32_16x16x32_bf16(wa13, q3_, a1_, 0,0,0); \
        const float h00_ = tanh_fast(a0_[0] + (XM0).x);                       \
        const float h01_ = tanh_fast(a0_[1] + (XM0).y);                       \
        const float h02_ = tanh_fast(a0_[2] + (XM0).z);                       \
        const float h03_ = tanh_fast(a0_[3] + (XM0).w);                       \
        const float h10_ = tanh_fast(a1_[0] + (XM1).x);                       \
        const float h11_ = tanh_fast(a1_[1] + (XM1).y);                       \
        const float h12_ = tanh_fast(a1_[2] + (XM1).z);                       \
        const float h13_ = tanh_fast(a1_[3] + (XM1).w);                       \
        hmax00 = fmaxf(hmax00, h00_); hsum00 += h00_;                         \
        hmax01 = fmaxf(hmax01, h01_); hsum01 += h01_;                         \
        hmax02 = fmaxf(hmax02, h02_); hsum02 += h02_;                         \
        hmax03 = fmaxf(hmax03, h03_); hsum03 += h03_;                         \
        hmax10 = fmaxf(hmax10, h10_); hsum10 += h10_;                         \
        hmax11 = fmaxf(hmax11, h11_); hsum11 += h11_;                         \
        hmax12 = fmaxf(hmax12, h12_); hsum12 += h12_;                         \
        hmax13 = fmaxf(hmax13, h13_); hsum13 += h13_;                         \
        uint2 wv0_, wv1_;                                                     \
        wv0_.x = bf16_rtne(h00_) | (bf16_rtne(h01_) << 16);                   \
        wv0_.y = bf16_rtne(h02_) | (bf16_rtne(h03_) << 16);                   \
        wv1_.x = bf16_rtne(h10_) | (bf16_rtne(h11_) << 16);                   \
        wv1_.y = bf16_rtne(h12_) | (bf16_rtne(h13_) << 16);                   \
        *(uint2*)(hwr_ + wro0) = wv0_;                                        \
        *(uint2*)(hwr_ + wro1) = wv1_;                                        \
        __syncthreads();                                                      \
    } while (0)

    for (int s = 0; s < SEQ; s += 4) {
        const int p3 = (s + 3 < SEQ) ? s + 3 : SEQ - 1;
        const int p4 = (s + 4 < SEQ) ? s + 4 : SEQ - 1;
        const int p5 = (s + 5 < SEQ) ? s + 5 : SEQ - 1;
        const int p6 = (s + 6 < SEQ) ? s + 6 : SEQ - 1;
        RSTEP(0, xA0, xA1, xD0, xD1, p3);   // step s   reads Hb0
        RSTEP(1, xB0, xB1, xA0, xA1, p4);   // step s+1 reads Hb1
        RSTEP(0, xC0, xC1, xB0, xB1, p5);   // step s+2
        RSTEP(1, xD0, xD1, xC0, xC1, p6);   // step s+3
    }
#undef RSTEP

    // pooling + FC: lane owns (m, 8 n-values)
    float part = 0.f;
    part += fcw[n00 + 0] * hmax00 + fcw[HID + n00 + 0] * (hsum00 * (1.f / 512.f));
    part += fcw[n00 + 1] * hmax01 + fcw[HID + n00 + 1] * (hsum01 * (1.f / 512.f));
    part += fcw[n00 + 2] * hmax02 + fcw[HID + n00 + 2] * (hsum02 * (1.f / 512.f));
    part += fcw[n00 + 3] * hmax03 + fcw[HID + n00 + 3] * (hsum03 * (1.f / 512.f));
    part += fcw[n01 + 0] * hmax10 + fcw[HID + n01 + 0] * (hsum10 * (1.f / 512.f));
    part += fcw[n01 + 1] * hmax11 + fcw[HID + n01 + 1] * (hsum11 * (1.f / 512.f));
    part += fcw[n01 + 2] * hmax12 + fcw[HID + n01 + 2] * (hsum12 * (1.f / 512.f));
    part += fcw[n01 + 3] * hmax13 + fcw[HID + n01 + 3] * (hsum13 * (1.f / 512.f));
    red[t] = part;
    __syncthreads();
    if (t < 16) {
        float v = 0.f;
        #pragma unroll
        for (int j = 0; j < 16; ++j) v += red[t + 16 * j];
        out[b0 + t] = v + fcb[0];
    }
}

// ---------------------------------------------------------------------------
extern "C" void kernel_launch(void* const* d_in, const int* in_sizes, int n_in,
                              void* d_out, int out_size, void* d_ws, size_t ws_size,
                              hipStream_t stream)
{
    const int*   x   = (const int*)  d_in[0];
    const float* emb = (const float*)d_in[1];
    const float* Wih = (const float*)d_in[2];
    const float* Whh = (const float*)d_in[3];
    const float* bih = (const float*)d_in[4];
    const float* bhh = (const float*)d_in[5];
    const float* fcw = (const float*)d_in[6];
    const float* fcb = (const float*)d_in[7];

    float* P = (float*)d_ws;   // exactly VOCAB*HID*4 = 25.6 MB (R1-proven)

    proj_persist<<<256, 512, 0, stream>>>(emb, Wih, bih, bhh, P);
    rnn_mfma<<<16, 256, 0, stream>>>(x, Whh, P, fcw, fcb, (float*)d_out);
}

// Round 22
// 182.952 us; speedup vs baseline: 1.3644x; 1.3644x over previous
//
#include <hip/hip_runtime.h>

#define HID    128
#define SEQ    512
#define BATCH  256
#define DIM    300
#define VOCAB  50000

typedef short bf16x8 __attribute__((ext_vector_type(8)));   // 8 bf16 = 4 VGPR
typedef float f32x4  __attribute__((ext_vector_type(4)));
typedef __fp16 half2_t __attribute__((ext_vector_type(2))); // matches cvt_pkrtz

#define KP     320      // padded K (10 x 32)
#define LST    328      // LDS row stride in bf16 (656 B, 16B-aligned)
#define TROWS  32       // vocab rows per tile
#define NTILES ((VOCAB + TROWS - 1) / TROWS)   // 1563

__device__ __forceinline__ unsigned bf16_rtne(float v)
{
    unsigned u = __float_as_uint(v);
    return (u + 0x7FFFu + ((u >> 16) & 1u)) >> 16;
}

// ---------------------------------------------------------------------------
// Kernel A (R15-proven, ~33 µs): persistent MFMA proj — byte-identical.
// ---------------------------------------------------------------------------
__global__ __launch_bounds__(512)
void proj_persist(const float* __restrict__ emb,
                  const float* __restrict__ Wih,
                  const float* __restrict__ bih,
                  const float* __restrict__ bhh,
                  float* __restrict__ P)
{
    __shared__ unsigned short Bt[128 * LST];       // W_ih bf16 (84 KB)
    __shared__ unsigned short At[2 * TROWS * LST]; // emb dbuf (2 x 21 KB)

    const int t   = threadIdx.x;
    const int bid = blockIdx.x;

    for (int c = t; c < 128 * 40; c += 512) {
        const int row = c / 40;
        const int ch  = c - row * 40;
        const float* src = Wih + (size_t)row * DIM;
        const int k0 = ch * 8;
        unsigned p0, p1, p2, p3;
        if (k0 + 8 <= DIM) {
            const float4 a = *(const float4*)(src + k0);
            const float4 b = *(const float4*)(src + k0 + 4);
            p0 = bf16_rtne(a.x) | (bf16_rtne(a.y) << 16);
            p1 = bf16_rtne(a.z) | (bf16_rtne(a.w) << 16);
            p2 = bf16_rtne(b.x) | (bf16_rtne(b.y) << 16);
            p3 = bf16_rtne(b.z) | (bf16_rtne(b.w) << 16);
        } else {
            unsigned q[8];
            #pragma unroll
            for (int e = 0; e < 8; ++e) {
                const int k = k0 + e;
                q[e] = (k < DIM) ? bf16_rtne(src[k]) : 0u;
            }
            p0 = q[0] | (q[1] << 16);  p1 = q[2] | (q[3] << 16);
            p2 = q[4] | (q[5] << 16);  p3 = q[6] | (q[7] << 16);
        }
        uint4 o = {p0, p1, p2, p3};
        *(uint4*)(&Bt[row * LST + k0]) = o;
    }

#define STAGE_EMB(tl, bf) do {                                                \
        const int v0_ = (tl) * TROWS;                                         \
        for (int c = t; c < TROWS * 40; c += 512) {                           \
            const int row = c / 40;                                           \
            const int ch  = c - row * 40;                                     \
            int grow = v0_ + row; if (grow > VOCAB - 1) grow = VOCAB - 1;     \
            const float* src = emb + (size_t)grow * DIM;                      \
            const int k0 = ch * 8;                                            \
            unsigned p0, p1, p2, p3;                                          \
            if (k0 + 8 <= DIM) {                                              \
                const float4 a = *(const float4*)(src + k0);                  \
                const float4 b = *(const float4*)(src + k0 + 4);              \
                p0 = bf16_rtne(a.x) | (bf16_rtne(a.y) << 16);                 \
                p1 = bf16_rtne(a.z) | (bf16_rtne(a.w) << 16);                 \
                p2 = bf16_rtne(b.x) | (bf16_rtne(b.y) << 16);                 \
                p3 = bf16_rtne(b.z) | (bf16_rtne(b.w) << 16);                 \
            } else {                                                          \
                unsigned q[8];                                                \
                _Pragma("unroll")                                             \
                for (int e = 0; e < 8; ++e) {                                 \
                    const int k = k0 + e;                                     \
                    q[e] = (k < DIM) ? bf16_rtne(src[k]) : 0u;                \
                }                                                             \
                p0 = q[0] | (q[1] << 16);  p1 = q[2] | (q[3] << 16);          \
                p2 = q[4] | (q[5] << 16);  p3 = q[6] | (q[7] << 16);          \
            }                                                                 \
            uint4 o = {p0, p1, p2, p3};                                       \
            *(uint4*)(&At[(bf) * (TROWS * LST) + row * LST + k0]) = o;        \
        }                                                                     \
    } while (0)

    const int lane = t & 63;
    const int w    = t >> 6;
    const int mt   = w >> 2;
    const int np   = w & 3;
    const int lm   = lane & 15;
    const int kg   = lane >> 4;

    STAGE_EMB(bid, 0);
    __syncthreads();

    int buf = 0;
    for (int tile = bid; tile < NTILES; tile += 256) {
        if (tile + 256 < NTILES) STAGE_EMB(tile + 256, buf ^ 1);

        const unsigned short* arow = &At[buf * (TROWS * LST)
                                         + (mt * 16 + lm) * LST + kg * 8];
        const unsigned short* brow = &Bt[(np * 32 + lm) * LST + kg * 8];

        f32x4 acc0 = {0.f,0.f,0.f,0.f}, acc1 = {0.f,0.f,0.f,0.f};
        #pragma unroll
        for (int k0 = 0; k0 < KP; k0 += 32) {
            const bf16x8 af = *(const bf16x8*)(arow + k0);
            const bf16x8 b0 = *(const bf16x8*)(brow + k0);
            const bf16x8 b1 = *(const bf16x8*)(brow + 16 * LST + k0);
            acc0 = __builtin_amdgcn_mfma_f32_16x16x32_bf16(af, b0, acc0, 0, 0, 0);
            acc1 = __builtin_amdgcn_mfma_f32_16x16x32_bf16(af, b1, acc1, 0, 0, 0);
        }

        const int rbase = tile * TROWS + mt * 16 + kg * 4;
        #pragma unroll
        for (int nt2 = 0; nt2 < 2; ++nt2) {
            const int h = (np * 2 + nt2) * 16 + lm;
            const float bb = bih[h] + bhh[h];
            const f32x4 a = nt2 ? acc1 : acc0;
            #pragma unroll
            for (int r = 0; r < 4; ++r) {
                const int row = rbase + r;
                if (row < VOCAB) P[(size_t)row * HID + h] = a[r] + bb;
            }
        }

        __syncthreads();
        buf ^= 1;
    }
#undef STAGE_EMB
}

// ---------------------------------------------------------------------------
// Kernel B (R18-proven, 145 µs): RNN, R8 chassis, h as F16 pairs in LDS +
// v_dot2_f32_f16 (no unpack chain). W pre-converted via cvt_pkrtz.
// ---------------------------------------------------------------------------
__device__ __forceinline__ float quad_sum(float v)
{
    int x1 = __builtin_amdgcn_update_dpp(0, __float_as_int(v), 0xB1, 0xF, 0xF, true);
    v += __int_as_float(x1);
    int x2 = __builtin_amdgcn_update_dpp(0, __float_as_int(v), 0x4E, 0xF, 0xF, true);
    v += __int_as_float(x2);
    return v;
}

#if defined(__has_builtin)
#  if __has_builtin(__builtin_amdgcn_fdot2)
#    define HAVE_FDOT2 1
#  endif
#endif

__device__ __forceinline__ half2_t u2h(unsigned u)
{
    union { unsigned u; half2_t h; } c; c.u = u; return c.h;
}

__global__ __launch_bounds__(512)
void rnn_kernel(const int* __restrict__ x,
                const float* __restrict__ Whh,
                const float* __restrict__ P,
                const float* __restrict__ fcw,
                const float* __restrict__ fcb,
                float* __restrict__ out)
{
    __shared__ __align__(16) unsigned short h0b[HID];   // f16 h (256 B)
    __shared__ __align__(16) unsigned short h1b[HID];
    __shared__ int   toff[SEQ];
    __shared__ float xb[2 * 64 * HID];
    __shared__ float red[HID];

    const int t  = threadIdx.x;
    const int b  = blockIdx.x;
    const int i  = t >> 2;
    const int kq = t & 3;

    toff[t] = x[b * SEQ + t] * HID;
    if (t < HID) h0b[t] = 0;   // f16 zero

    // W_hh[i][kq*32 + pj*8 .. +8] as 16 packed f16 pairs (pj=(j+kq)&3)
    half2_t wh[16];
    #pragma unroll
    for (int j = 0; j < 4; ++j) {
        const int pj = (j + kq) & 3;
        const float4 vA = *(const float4*)(Whh + (size_t)i * HID + kq * 32 + pj * 8);
        const float4 vB = *(const float4*)(Whh + (size_t)i * HID + kq * 32 + pj * 8 + 4);
        wh[j*4+0] = __builtin_amdgcn_cvt_pkrtz(vA.x, vA.y);
        wh[j*4+1] = __builtin_amdgcn_cvt_pkrtz(vA.z, vA.w);
        wh[j*4+2] = __builtin_amdgcn_cvt_pkrtz(vB.x, vB.y);
        wh[j*4+3] = __builtin_amdgcn_cvt_pkrtz(vB.z, vB.w);
    }
    __syncthreads();

#define STAGE(cn) do {                                                        \
        const int w_ = t >> 6, l_ = t & 63;                                   \
        const int base_ = ((cn) & 1) * (64 * HID);                            \
        _Pragma("unroll")                                                     \
        for (int q_ = 0; q_ < 4; ++q_) {                                      \
            const int row_ = w_ * 8 + q_ * 2 + (l_ >> 5);                     \
            const int col_ = (l_ & 31) * 4;                                   \
            const int off_ = toff[(cn) * 64 + row_] + col_;                   \
            const float4 v_ = *(const float4*)(P + off_);                     \
            *(float4*)(&xb[base_ + row_ * HID + col_]) = v_;                  \
        }                                                                     \
    } while (0)

    STAGE(0);
    __syncthreads();

    float hmax = -3.0e38f, hsum = 0.f;

#if HAVE_FDOT2
#define JBLK(HRD, J, AC) do {                                                 \
        const int pj_ = ((J) + kq) & 3;                                       \
        const uint4 q_ = *(const uint4*)((HRD) + kq * 32 + pj_ * 8);          \
        AC = __builtin_amdgcn_fdot2(wh[(J)*4+0], u2h(q_.x), AC, false);       \
        AC = __builtin_amdgcn_fdot2(wh[(J)*4+1], u2h(q_.y), AC, false);       \
        AC = __builtin_amdgcn_fdot2(wh[(J)*4+2], u2h(q_.z), AC, false);       \
        AC = __builtin_amdgcn_fdot2(wh[(J)*4+3], u2h(q_.w), AC, false);       \
    } while (0)
#else
#define JBLK(HRD, J, AC) do {                                                 \
        const int pj_ = ((J) + kq) & 3;                                       \
        const uint4 q_ = *(const uint4*)((HRD) + kq * 32 + pj_ * 8);          \
        _Pragma("unroll")                                                     \
        for (int e_ = 0; e_ < 4; ++e_) {                                      \
            const unsigned u_ = (e_==0)?q_.x:(e_==1)?q_.y:(e_==2)?q_.z:q_.w;  \
            const half2_t h2_ = u2h(u_);                                      \
            AC = fmaf((float)wh[(J)*4+e_].x, (float)h2_.x, AC);               \
            AC = fmaf((float)wh[(J)*4+e_].y, (float)h2_.y, AC);               \
        }                                                                     \
    } while (0)
#endif

#define STEP(HRD, HWR, XPTR, SOFF) do {                                       \
        const float xt = (XPTR)[(SOFF) * HID];                                \
        float ac0 = 0.f, ac1 = 0.f, ac2 = 0.f, ac3 = 0.f;                     \
        JBLK(HRD, 0, ac0);                                                    \
        JBLK(HRD, 1, ac1);                                                    \
        JBLK(HRD, 2, ac2);                                                    \
        JBLK(HRD, 3, ac3);                                                    \
        float acc = (ac0 + ac1) + (ac2 + ac3);                                \
        acc = quad_sum(acc);                                                  \
        const float z = xt + acc;                                             \
        const float e = __builtin_amdgcn_exp2f(z * 2.8853900817779268f);      \
        const float hnew = fmaf(-2.f, __builtin_amdgcn_rcpf(e + 1.f), 1.f);   \
        hmax = fmaxf(hmax, hnew);                                             \
        hsum += hnew;                                                         \
        union { __fp16 f; unsigned short u; } cv_;                            \
        cv_.f = (__fp16)hnew;                                                 \
        (HWR)[i] = cv_.u;   /* 4 dup lanes: same value, same address */       \
        __syncthreads();                                                      \
    } while (0)

    for (int c = 0; c < 8; ++c) {
        if (c < 7) STAGE(c + 1);
        const float* xp = &xb[(c & 1) * (64 * HID) + i];
        #pragma unroll 4
        for (int u = 0; u < 32; ++u) {
            STEP(h0b, h1b, xp, u * 2);
            STEP(h1b, h0b, xp, u * 2 + 1);
        }
    }
#undef STEP
#undef JBLK
#undef STAGE

    if (kq == 0)
        red[i] = fcw[i] * hmax + fcw[HID + i] * (hsum * (1.f / 512.f));
    __syncthreads();
    if (t < 64) {
        float v = red[t] + red[t + 64];
        #pragma unroll
        for (int m = 32; m >= 1; m >>= 1) v += __shfl_xor(v, m);
        if (t == 0) out[b] = v + fcb[0];
    }
}

// ---------------------------------------------------------------------------
extern "C" void kernel_launch(void* const* d_in, const int* in_sizes, int n_in,
                              void* d_out, int out_size, void* d_ws, size_t ws_size,
                              hipStream_t stream)
{
    const int*   x   = (const int*)  d_in[0];
    const float* emb = (const float*)d_in[1];
    const float* Wih = (const float*)d_in[2];
    const float* Whh = (const float*)d_in[3];
    const float* bih = (const float*)d_in[4];
    const float* bhh = (const float*)d_in[5];
    const float* fcw = (const float*)d_in[6];
    const float* fcb = (const float*)d_in[7];

    float* P = (float*)d_ws;   // exactly VOCAB*HID*4 = 25.6 MB (R1-proven)

    proj_persist<<<256, 512, 0, stream>>>(emb, Wih, bih, bhh, P);
    rnn_kernel<<<BATCH, 512, 0, stream>>>(x, Whh, P, fcw, fcb, (float*)d_out);
}